// Round 1
// baseline (128.539 us; speedup 1.0000x reference)
//
#include <hip/hip_runtime.h>

#define EPSV 1e-5f

// ---------------------------------------------------------------------------
// Kernel 1: fold the three branches into one 13x13 depthwise kernel + bias.
//   W_eff[c] = w_large[c]*scale_l  (+ w_small[c]*scale_s in center 3x3)
//              (+ scale_i at center tap)
//   bias[c]  = shift_l + shift_s + shift_i
// where scale = g/sqrt(v+eps), shift = b - m*scale.
// ---------------------------------------------------------------------------
__global__ __launch_bounds__(256) void fuse_weights(
    const float* __restrict__ w_large, const float* __restrict__ w_small,
    const float* __restrict__ g_l, const float* __restrict__ b_l,
    const float* __restrict__ m_l, const float* __restrict__ v_l,
    const float* __restrict__ g_s, const float* __restrict__ b_s,
    const float* __restrict__ m_s, const float* __restrict__ v_s,
    const float* __restrict__ g_i, const float* __restrict__ b_i,
    const float* __restrict__ m_i, const float* __restrict__ v_i,
    float* __restrict__ wf, float* __restrict__ bf) {
    const int c = blockIdx.x;
    const int t = threadIdx.x;
    const float sl = g_l[c] / sqrtf(v_l[c] + EPSV);
    const float ss = g_s[c] / sqrtf(v_s[c] + EPSV);
    const float si = g_i[c] / sqrtf(v_i[c] + EPSV);
    if (t < 169) {
        const int ky = t / 13, kx = t % 13;
        float w = w_large[c * 169 + t] * sl;
        if (ky >= 5 && ky <= 7 && kx >= 5 && kx <= 7)
            w += w_small[c * 9 + (ky - 5) * 3 + (kx - 5)] * ss;
        if (t == 6 * 13 + 6) w += si;
        wf[c * 169 + t] = w;
    }
    if (t == 0)
        bf[c] = (b_l[c] - m_l[c] * sl) + (b_s[c] - m_s[c] * ss) +
                (b_i[c] - m_i[c] * si);
}

// ---------------------------------------------------------------------------
// Kernel 2: depthwise 13x13 conv + bias over [N=16, C=384, 64, 64] f32.
// One block per (n,c) image. Zero-padded 76x76 tile staged in LDS (halo is
// genuine conv padding -> zero HBM over-fetch). Each thread: one 1x16 output
// strip; per tap-row, 7 ds_read_b128 fill a 28-float register window that
// feeds 13x16 = 208 FMAs.
// ---------------------------------------------------------------------------
#define TW 76  // padded tile width/height (64 + 2*6); 76*4B = 304B, 16B-aligned rows

__global__ __launch_bounds__(256) void dwconv13(
    const float* __restrict__ x, const float* __restrict__ wf,
    const float* __restrict__ bf, float* __restrict__ out) {
    __shared__ __align__(16) float tile[TW * TW];
    __shared__ float wl[169];
    __shared__ float bias_s;

    const int t = threadIdx.x;
    const int img = blockIdx.x;        // n*384 + c
    const int c = img % 384;
    const size_t base = (size_t)img * 4096;

    // zero whole tile (covers halo), then overwrite interior
    for (int i = t; i < TW * TW; i += 256) tile[i] = 0.0f;
    if (t < 169) wl[t] = wf[c * 169 + t];
    if (t == 200) bias_s = bf[c];
    __syncthreads();

    {
        const int r = t >> 2;                 // 0..63
        const int cs = (t & 3) << 4;          // 0,16,32,48
        const float4* src = (const float4*)(x + base + r * 64 + cs);
        float* dst = &tile[(r + 6) * TW + cs + 6];
#pragma unroll
        for (int q = 0; q < 4; ++q) {
            const float4 v = src[q];
            dst[4 * q + 0] = v.x;
            dst[4 * q + 1] = v.y;
            dst[4 * q + 2] = v.z;
            dst[4 * q + 3] = v.w;
        }
    }
    __syncthreads();

    const int row = t >> 2;
    const int c0 = (t & 3) << 4;
    const float bv = bias_s;
    float acc[16];
#pragma unroll
    for (int j = 0; j < 16; ++j) acc[j] = bv;

    const float* trow = &tile[row * TW + c0];
    for (int dr = 0; dr < 13; ++dr) {
        float xw[28];
        const float4* p = (const float4*)(trow + dr * TW);
#pragma unroll
        for (int q = 0; q < 7; ++q) {
            const float4 v = p[q];
            xw[4 * q + 0] = v.x;
            xw[4 * q + 1] = v.y;
            xw[4 * q + 2] = v.z;
            xw[4 * q + 3] = v.w;
        }
        const float* wr = &wl[dr * 13];
#pragma unroll
        for (int dc = 0; dc < 13; ++dc) {
            const float wv = wr[dc];
#pragma unroll
            for (int j = 0; j < 16; ++j)
                acc[j] = fmaf(xw[dc + j], wv, acc[j]);
        }
    }

    float4* op = (float4*)(out + base + row * 64 + c0);
#pragma unroll
    for (int q = 0; q < 4; ++q)
        op[q] = make_float4(acc[4 * q + 0], acc[4 * q + 1], acc[4 * q + 2],
                            acc[4 * q + 3]);
}

// ---------------------------------------------------------------------------
extern "C" void kernel_launch(void* const* d_in, const int* in_sizes, int n_in,
                              void* d_out, int out_size, void* d_ws,
                              size_t ws_size, hipStream_t stream) {
    const float* x = (const float*)d_in[0];
    const float* w_large = (const float*)d_in[1];
    const float* w_small = (const float*)d_in[2];
    const float* g_l = (const float*)d_in[3];
    const float* b_l = (const float*)d_in[4];
    const float* m_l = (const float*)d_in[5];
    const float* v_l = (const float*)d_in[6];
    const float* g_s = (const float*)d_in[7];
    const float* b_s = (const float*)d_in[8];
    const float* m_s = (const float*)d_in[9];
    const float* v_s = (const float*)d_in[10];
    const float* g_i = (const float*)d_in[11];
    const float* b_i = (const float*)d_in[12];
    const float* m_i = (const float*)d_in[13];
    const float* v_i = (const float*)d_in[14];
    float* outp = (float*)d_out;

    float* wf = (float*)d_ws;            // 384*169 floats
    float* bfp = wf + 384 * 169;         // 384 floats

    fuse_weights<<<384, 256, 0, stream>>>(w_large, w_small, g_l, b_l, m_l, v_l,
                                          g_s, b_s, m_s, v_s, g_i, b_i, m_i,
                                          v_i, wf, bfp);
    dwconv13<<<16 * 384, 256, 0, stream>>>(x, wf, bfp, outp);
}

// Round 2
// 117.171 us; speedup vs baseline: 1.0970x; 1.0970x over previous
//
#include <hip/hip_runtime.h>

#define EPSV 1e-5f
#define TW 76          // padded tile width: 6 + 64 + 6 floats; 19 chunks of 16B
#define WROWS 19       // padded weight rows: 3 zero + 13 real + 3 zero
#define WSTRIDE (WROWS * 13)   // 247 floats per channel

// ---------------------------------------------------------------------------
// Kernel 1: fold the three branches into one 13x13 depthwise kernel + bias,
// stored ZERO-PADDED to 19 rows (rows 0..2 and 16..18 are zero) so the conv
// kernel can index row (dr - i + 3) for dr in 0..15, i in 0..3 branch-free.
// ---------------------------------------------------------------------------
__global__ __launch_bounds__(256) void fuse_weights(
    const float* __restrict__ w_large, const float* __restrict__ w_small,
    const float* __restrict__ g_l, const float* __restrict__ b_l,
    const float* __restrict__ m_l, const float* __restrict__ v_l,
    const float* __restrict__ g_s, const float* __restrict__ b_s,
    const float* __restrict__ m_s, const float* __restrict__ v_s,
    const float* __restrict__ g_i, const float* __restrict__ b_i,
    const float* __restrict__ m_i, const float* __restrict__ v_i,
    float* __restrict__ wpad, float* __restrict__ bf) {
    const int c = blockIdx.x;
    const int t = threadIdx.x;
    const float sl = g_l[c] * rsqrtf(v_l[c] + EPSV);
    const float ss = g_s[c] * rsqrtf(v_s[c] + EPSV);
    const float si = g_i[c] * rsqrtf(v_i[c] + EPSV);
    if (t < WSTRIDE) {
        const int p = t / 13, kx = t % 13;
        const int ky = p - 3;
        float w = 0.0f;
        if (ky >= 0 && ky <= 12) {
            w = w_large[c * 169 + ky * 13 + kx] * sl;
            if (ky >= 5 && ky <= 7 && kx >= 5 && kx <= 7)
                w += w_small[c * 9 + (ky - 5) * 3 + (kx - 5)] * ss;
            if (ky == 6 && kx == 6) w += si;
        }
        wpad[c * WSTRIDE + t] = w;
    }
    if (t == 0)
        bf[c] = (b_l[c] - m_l[c] * sl) + (b_s[c] - m_s[c] * ss) +
                (b_i[c] - m_i[c] * si);
}

// ---------------------------------------------------------------------------
// Kernel 2: depthwise 13x13 + bias over [16,384,64,64] f32.
// One block per (n,c) image; 256 threads; thread (rg=t>>4, cg=t&15) computes
// a 4x4 output block. Padded 76x76 image in LDS. Per tap row: 4 ds_read_b128
// (16 consecutive floats at 4*cg) -> conflict-free (8 consecutive lanes hit
// 8 consecutive 16B chunks); each tap row feeds up to 4 accumulator rows.
// Weights are wave-uniform, read from global -> s_load -> SGPR FMA operand.
// ---------------------------------------------------------------------------
__global__ __launch_bounds__(256) void dwconv13(
    const float* __restrict__ x, const float* __restrict__ wpad,
    const float* __restrict__ bf, float* __restrict__ out) {
    __shared__ __align__(16) float tile[TW * TW];

    const int t = threadIdx.x;
    const int img = blockIdx.x;          // n*384 + c
    const int c = img % 384;
    const size_t base = (size_t)img * 4096;

    // ---- stage interior (rows/cols 6..69) ----
    {
        const int r = t >> 2;                 // 0..63
        const int cs = (t & 3) << 4;          // 0,16,32,48
        const float4* src = (const float4*)(x + base + r * 64 + cs);
        float* dst = &tile[(r + 6) * TW + cs + 6];
#pragma unroll
        for (int q = 0; q < 4; ++q) {
            const float4 v = src[q];
            dst[4 * q + 0] = v.x;
            dst[4 * q + 1] = v.y;
            dst[4 * q + 2] = v.z;
            dst[4 * q + 3] = v.w;
        }
    }
    // ---- zero halo only (disjoint from interior: no barrier needed between) ----
    for (int i = t; i < 912; i += 256) {     // top 6 + bottom 6 full rows
        const int r = i / TW;
        const int cc = i - r * TW;
        const int rr = (r < 6) ? r : r + 64;
        tile[rr * TW + cc] = 0.0f;
    }
    for (int i = t; i < 768; i += 256) {     // left/right 6 cols, rows 6..69
        const int r = 6 + i / 12;
        const int cc = i - (r - 6) * 12;
        const int cc2 = (cc < 6) ? cc : cc + 64;
        tile[r * TW + cc2] = 0.0f;
    }
    __syncthreads();

    const int rg = t >> 4;   // 0..15 -> output rows 4*rg..4*rg+3
    const int cg = t & 15;   // 0..15 -> output cols 4*cg..4*cg+3
    const float* trow0 = &tile[(4 * rg) * TW + 4 * cg];
    const float* wc = wpad + c * WSTRIDE;
    const float bv = bf[c];

    float acc[4][4];
#pragma unroll
    for (int i = 0; i < 4; ++i)
#pragma unroll
        for (int j = 0; j < 4; ++j) acc[i][j] = bv;

    float xw[16];

#define LROW(dr_)                                                   \
    {                                                               \
        const float4* p4 = (const float4*)(trow0 + (dr_) * TW);     \
        *(float4*)&xw[0] = p4[0];                                   \
        *(float4*)&xw[4] = p4[1];                                   \
        *(float4*)&xw[8] = p4[2];                                   \
        *(float4*)&xw[12] = p4[3];                                  \
    }

#define TAP(i_, dr_)                                                \
    {                                                               \
        const float* wr_ = wc + ((dr_) - (i_) + 3) * 13;            \
        _Pragma("unroll") for (int dc = 0; dc < 13; ++dc) {         \
            const float w_ = wr_[dc];                               \
            _Pragma("unroll") for (int j = 0; j < 4; ++j)           \
                acc[i_][j] = fmaf(xw[dc + j], w_, acc[i_][j]);      \
        }                                                           \
    }

    // prologue: tap rows 0..2 (partial accumulator coverage)
    LROW(0); TAP(0, 0);
    LROW(1); TAP(0, 1); TAP(1, 1);
    LROW(2); TAP(0, 2); TAP(1, 2); TAP(2, 2);
    // main: tap rows 3..12, all 4 accumulator rows valid
    for (int dr = 3; dr <= 12; ++dr) {
        LROW(dr);
        TAP(0, dr); TAP(1, dr); TAP(2, dr); TAP(3, dr);
    }
    // epilogue: tap rows 13..15
    LROW(13); TAP(1, 13); TAP(2, 13); TAP(3, 13);
    LROW(14); TAP(2, 14); TAP(3, 14);
    LROW(15); TAP(3, 15);

#undef LROW
#undef TAP

    float* ob = out + base + (4 * rg) * 64 + 4 * cg;
#pragma unroll
    for (int i = 0; i < 4; ++i)
        *(float4*)(ob + i * 64) =
            make_float4(acc[i][0], acc[i][1], acc[i][2], acc[i][3]);
}

// ---------------------------------------------------------------------------
extern "C" void kernel_launch(void* const* d_in, const int* in_sizes, int n_in,
                              void* d_out, int out_size, void* d_ws,
                              size_t ws_size, hipStream_t stream) {
    const float* x = (const float*)d_in[0];
    const float* w_large = (const float*)d_in[1];
    const float* w_small = (const float*)d_in[2];
    const float* g_l = (const float*)d_in[3];
    const float* b_l = (const float*)d_in[4];
    const float* m_l = (const float*)d_in[5];
    const float* v_l = (const float*)d_in[6];
    const float* g_s = (const float*)d_in[7];
    const float* b_s = (const float*)d_in[8];
    const float* m_s = (const float*)d_in[9];
    const float* v_s = (const float*)d_in[10];
    const float* g_i = (const float*)d_in[11];
    const float* b_i = (const float*)d_in[12];
    const float* m_i = (const float*)d_in[13];
    const float* v_i = (const float*)d_in[14];
    float* outp = (float*)d_out;

    float* wpad = (float*)d_ws;                 // 384*247 floats
    float* bfp = wpad + 384 * WSTRIDE;          // 384 floats

    fuse_weights<<<384, 256, 0, stream>>>(w_large, w_small, g_l, b_l, m_l, v_l,
                                          g_s, b_s, m_s, v_s, g_i, b_i, m_i,
                                          v_i, wpad, bfp);
    dwconv13<<<16 * 384, 256, 0, stream>>>(x, wpad, bfp, outp);
}